// Round 4
// baseline (523.638 us; speedup 1.0000x reference)
//
#include <hip/hip_runtime.h>

// GAT layer, N=8192, D=256. R4: swapped-QK^T flash attention.
//  - S^T = mfma(A=h_tile, B=g_regs): each lane holds 8 S values of ONE q-row
//    -> wave-local online softmax (shfl_xor 16/32), no S round-trip via LDS.
//  - each wave owns a 32-col kv half; per-wave (m,l) partials, 4-way combine.
//  - h-tile hi+lo staged in LDS (XOR-swizzled) via global_load_lds, single
//    buffer, 2 barriers/tile; vstage issued BEFORE stage so PV's vmcnt wait
//    leaves stage loads in flight; adj/ax prefetched one full tile ahead.
// Split-bf16 (hi+lo) 3-term MFMA for the logit chain; plain bf16 elsewhere.

typedef __attribute__((ext_vector_type(8))) short bf16x8;
typedef __attribute__((ext_vector_type(4))) short s16x4;
typedef __attribute__((ext_vector_type(4))) float f32x4;

#define NN 8192
#define DD 256
#define NSPLIT 2
#define NPART (NSPLIT * 2)
#define CHUNK (NN / NSPLIT)
#define KVB 64
#define BM 32
#define NT (CHUNK / KVB)

#define MFMA(a, b, c) __builtin_amdgcn_mfma_f32_16x16x32_bf16(a, b, c, 0, 0, 0)
#define BAR_LGKM() asm volatile("s_waitcnt lgkmcnt(0)\n\ts_barrier" ::: "memory")

__device__ __forceinline__ short f2bf(float f) {
  union { float f; unsigned u; } v; v.f = f;
  unsigned r = v.u + 0x7fffu + ((v.u >> 16) & 1u);  // RNE
  return (short)(r >> 16);
}
__device__ __forceinline__ float bf2f(short b) {
  union { unsigned u; float f; } v; v.u = ((unsigned)(unsigned short)b) << 16;
  return v.f;
}

typedef __attribute__((address_space(3))) unsigned lds_u32;
typedef const __attribute__((address_space(1))) unsigned glb_u32;
__device__ __forceinline__ void gl2lds16(const void* g, void* l) {
  __builtin_amdgcn_global_load_lds((glb_u32*)g, (lds_u32*)l, 16, 0, 0);
}

// f32 -> (hi, lo) bf16 split, elementwise
__global__ __launch_bounds__(256) void cvt_split_kernel(const float* __restrict__ in,
                                                        short* __restrict__ hi,
                                                        short* __restrict__ lo, int n) {
  for (int i = blockIdx.x * blockDim.x + threadIdx.x; i < n; i += gridDim.x * blockDim.x) {
    float f = in[i];
    short h = f2bf(f);
    hi[i] = h;
    lo[i] = f2bf(f - bf2f(h));
  }
}

// featT[c][i] = bf16(feat[i][c])
__global__ __launch_bounds__(256) void featT_kernel(const float* __restrict__ feat,
                                                    short* __restrict__ fT) {
  int c = blockIdx.y;
  int i = blockIdx.x * 256 + threadIdx.x;
  fT[c * NN + i] = f2bf(feat[i * DD + c]);
}

// 256x256 f32 -> transposed bf16 (optionally split hi/lo)
__global__ __launch_bounds__(256) void transpose_split_kernel(const float* __restrict__ in,
                                                              short* __restrict__ tHi,
                                                              short* __restrict__ tLo) {
  int r = blockIdx.x, c = threadIdx.x;
  float f = in[r * DD + c];
  short h = f2bf(f);
  tHi[c * DD + r] = h;
  if (tLo) tLo[c * DD + r] = f2bf(f - bf2f(h));
}

// C[64x64 tile] = A @ BT^T over K=256 (+optional split / second product / ELU)
__global__ __launch_bounds__(256) void gemm_bt64_kernel(
    const short* __restrict__ Ahi, const short* __restrict__ Alo,
    const short* __restrict__ BThi, const short* __restrict__ BTlo,
    const short* __restrict__ A2, const short* __restrict__ BT2,
    short* __restrict__ outHi, short* __restrict__ outLo,
    float* __restrict__ outF, int doElu) {
  const int lane = threadIdx.x & 63;
  const int w = threadIdx.x >> 6;
  const int l15 = lane & 15;
  const int koff = (lane >> 4) * 8;
  const int row0 = blockIdx.x * 64 + w * 16;
  const int col0 = blockIdx.y * 64;
  f32x4 acc[4] = {};
  const int aoff = (row0 + l15) * DD + koff;
#pragma unroll
  for (int kk = 0; kk < 8; ++kk) {
    bf16x8 ah = *(const bf16x8*)(Ahi + aoff + kk * 32);
#pragma unroll
    for (int cf = 0; cf < 4; ++cf) {
      int boff = (col0 + cf * 16 + l15) * DD + kk * 32 + koff;
      bf16x8 bh = *(const bf16x8*)(BThi + boff);
      acc[cf] = MFMA(ah, bh, acc[cf]);
      if (Alo) {
        bf16x8 al = *(const bf16x8*)(Alo + aoff + kk * 32);
        acc[cf] = MFMA(al, bh, acc[cf]);
      }
      if (BTlo) {
        bf16x8 bl = *(const bf16x8*)(BTlo + boff);
        acc[cf] = MFMA(ah, bl, acc[cf]);
      }
    }
  }
  if (A2) {
#pragma unroll
    for (int kk = 0; kk < 8; ++kk) {
      bf16x8 ah = *(const bf16x8*)(A2 + aoff + kk * 32);
#pragma unroll
      for (int cf = 0; cf < 4; ++cf) {
        bf16x8 bh = *(const bf16x8*)(BT2 + (col0 + cf * 16 + l15) * DD + kk * 32 + koff);
        acc[cf] = MFMA(ah, bh, acc[cf]);
      }
    }
  }
  const int crow = row0 + (lane >> 4) * 4;
#pragma unroll
  for (int cf = 0; cf < 4; ++cf) {
    int col = col0 + cf * 16 + l15;
#pragma unroll
    for (int r = 0; r < 4; ++r) {
      float v = acc[cf][r];
      if (doElu) v = (v > 0.f) ? v : expm1f(v);
      if (outF) outF[(crow + r) * DD + col] = v;
      if (outHi) {
        short hb = f2bf(v);
        outHi[(crow + r) * DD + col] = hb;
        if (outLo) outLo[(crow + r) * DD + col] = f2bf(v - bf2f(hb));
      }
    }
  }
}

// ax[i] = h[i,:]·a1, ay[i] = h[i,:]·a2
__global__ __launch_bounds__(256) void axay_kernel(const short* __restrict__ hHi,
                                                   const short* __restrict__ hLo,
                                                   const float* __restrict__ a1,
                                                   const float* __restrict__ a2,
                                                   float* __restrict__ ax,
                                                   float* __restrict__ ay) {
  const int lane = threadIdx.x & 63;
  const int w = threadIdx.x >> 6;
  const int row = blockIdx.x * 4 + w;
  float s1 = 0.f, s2 = 0.f;
#pragma unroll
  for (int j = 0; j < 4; ++j) {
    int k = lane * 4 + j;
    float hv = bf2f(hHi[row * DD + k]) + bf2f(hLo[row * DD + k]);
    s1 += hv * a1[k];
    s2 += hv * a2[k];
  }
#pragma unroll
  for (int m = 1; m < 64; m <<= 1) {
    s1 += __shfl_xor(s1, m);
    s2 += __shfl_xor(s2, m);
  }
  if (lane == 0) { ax[row] = s1; ay[row] = s2; }
}

// Swapped-QK^T flash attention. Block = 32 q-rows, 4 waves (wr = row half,
// wc = kv half). Per 64-col tile each wave handles 16 q x 32 kv.
__global__ __launch_bounds__(256, 2) void attn_kernel(
    const short* __restrict__ gHi, const short* __restrict__ gLo,
    const short* __restrict__ hHi, const short* __restrict__ hLo,
    const short* __restrict__ fT, const float* __restrict__ ax,
    const float* __restrict__ ay, const int* __restrict__ adj,
    short* __restrict__ numPart, float* __restrict__ mPart,
    float* __restrict__ lPart) {
  __shared__ short sH[KVB * DD];      // 32KB hi tile (rows 512B, XOR-swizzled)
  __shared__ short sHlo[KVB * DD];    // 32KB lo tile
  __shared__ short sPx[4][16][40];    // per-wave P exchange (80B rows)

  const int tid = threadIdx.x;
  const int lane = tid & 63;
  const int w = tid >> 6;
  const int wr = w >> 1, wc = w & 1;
  const int l15 = lane & 15;
  const int q0 = lane >> 4;
  const int row0 = blockIdx.x * BM;
  const int chunk = blockIdx.y;
  const int jbase = chunk * CHUNK;
  const int pidx = chunk * 2 + wc;
  const int qrow = row0 + wr * 16 + l15;  // this lane's q-row
  const int crow = q0 * 4;

  // hoist g (B-operand) hi+lo frags for the wave's 16 q rows
  bf16x8 ghi[8], glo[8];
#pragma unroll
  for (int kk = 0; kk < 8; ++kk) {
    int go = qrow * DD + kk * 32 + q0 * 8;
    ghi[kk] = *(const bf16x8*)(gHi + go);
    glo[kk] = *(const bf16x8*)(gLo + go);
  }
  const float ayq = ay[qrow];

  auto stage = [&](int jrow) {
#pragma unroll
    for (int R = 0; R < 8; ++R) {
      int dstb = R * 4096 + w * 1024 + lane * 16;  // linear byte in 32KB buf
      int lr = dstb >> 9;                           // local row
      int srcb = (dstb & 511) ^ ((lr & 7) << 4);    // pre-swizzled source col
      int so = (jrow + lr) * DD + (srcb >> 1);
      gl2lds16(hHi + so, (char*)sH + dstb);
      gl2lds16(hLo + so, (char*)sHlo + dstb);
    }
  };

  const size_t adjrow = (size_t)qrow * NN;
  float m_run = -__builtin_inff();
  float l_run = 0.f;
  f32x4 accpv[16] = {};  // hp[q = crow+r][d = dg*16 + l15]

  // prologue: stage tile 0; prefetch adj/ax tile 0
  stage(jbase);
  int4 a4[2]; float4 ax4[2];
  {
    int kb = jbase + wc * 32 + crow;
    a4[0] = *(const int4*)(adj + adjrow + kb);
    a4[1] = *(const int4*)(adj + adjrow + kb + 16);
    ax4[0] = *(const float4*)(ax + kb);
    ax4[1] = *(const float4*)(ax + kb + 16);
  }
  __syncthreads();

  for (int t = 0; t < NT; ++t) {
    const int j0 = jbase + t * KVB;
    // ---- prefetch adj/ax for tile t+1 (HBM latency ~ full tile) ----
    int4 a4n[2]; float4 ax4n[2];
    {
      int jn = (t + 1 < NT) ? (j0 + KVB) : jbase;
      int kb = jn + wc * 32 + crow;
      a4n[0] = *(const int4*)(adj + adjrow + kb);
      a4n[1] = *(const int4*)(adj + adjrow + kb + 16);
      ax4n[0] = *(const float4*)(ax + kb);
      ax4n[1] = *(const float4*)(ax + kb + 16);
    }
    // ---- swapped QK^T: S^T = h_tile . g^T (3-term split) ----
    f32x4 accs[2] = {};
#pragma unroll
    for (int cg = 0; cg < 2; ++cg) {
      const int row = wc * 32 + cg * 16 + l15;
      const int rb = row * 512;
      const int swz = (row & 7) << 4;
#pragma unroll
      for (int kk = 0; kk < 8; ++kk) {
        int bo = rb + ((kk * 64 + q0 * 16) ^ swz);
        bf16x8 ahh = *(const bf16x8*)((const char*)sH + bo);
        bf16x8 ahl = *(const bf16x8*)((const char*)sHlo + bo);
        accs[cg] = MFMA(ahh, ghi[kk], accs[cg]);
        accs[cg] = MFMA(ahh, glo[kk], accs[cg]);
        accs[cg] = MFMA(ahl, ghi[kk], accs[cg]);
      }
    }
    BAR_LGKM();  // all waves done reading sH; vm loads stay in flight
    // ---- vstage BEFORE stage: PV's vmcnt wait won't drain stage ----
    bf16x8 vstage[16];
#pragma unroll
    for (int dg = 0; dg < 16; ++dg)
      vstage[dg] = *(const bf16x8*)(fT + (size_t)(dg * 16 + l15) * NN +
                                    j0 + wc * 32 + q0 * 8);
    if (t + 1 < NT) stage(j0 + KVB);
    // ---- mask + bias + leaky (all in regs; lane = one q-row) ----
    float s8[2][4];
#pragma unroll
    for (int cg = 0; cg < 2; ++cg) {
      const int* ai = (const int*)&a4[cg];
      const float* axp = (const float*)&ax4[cg];
#pragma unroll
      for (int r = 0; r < 4; ++r) {
        float v = accs[cg][r] + axp[r] + ayq;
        v = (v > 0.f) ? v : 0.2f * v;
        s8[cg][r] = (ai[r] > 0) ? v : -9.0e15f;
      }
    }
    // ---- wave-local online softmax (row = l15; reduce over q0 groups) ----
    float tmax = s8[0][0];
#pragma unroll
    for (int cg = 0; cg < 2; ++cg)
#pragma unroll
      for (int r = 0; r < 4; ++r) tmax = fmaxf(tmax, s8[cg][r]);
    tmax = fmaxf(tmax, __shfl_xor(tmax, 16));
    tmax = fmaxf(tmax, __shfl_xor(tmax, 32));
    float m_new = fmaxf(m_run, tmax);
    float scale = __expf(m_run - m_new);
    float psum = 0.f;
    s16x4 pk[2];
#pragma unroll
    for (int cg = 0; cg < 2; ++cg)
#pragma unroll
      for (int r = 0; r < 4; ++r) {
        float p = __expf(s8[cg][r] - m_new);
        psum += p;
        pk[cg][r] = f2bf(p);
      }
    psum += __shfl_xor(psum, 16);
    psum += __shfl_xor(psum, 32);
    l_run = l_run * scale + psum;
    m_run = m_new;
    // ---- P exchange (per-wave LDS, intra-wave, no barrier) ----
    *(s16x4*)(&sPx[w][l15][4 * q0]) = pk[0];
    *(s16x4*)(&sPx[w][l15][16 + 4 * q0]) = pk[1];
    bf16x8 pa = *(const bf16x8*)(&sPx[w][l15][8 * q0]);
    // ---- rescale accpv (scale redistributed via 4 shuffles) ----
    float sc4[4];
#pragma unroll
    for (int r = 0; r < 4; ++r) sc4[r] = __shfl(scale, crow + r);
#pragma unroll
    for (int dg = 0; dg < 16; ++dg)
#pragma unroll
      for (int r = 0; r < 4; ++r) accpv[dg][r] *= sc4[r];
    // ---- PV: 16 MFMA (A = P, B = fT regs) ----
#pragma unroll
    for (int dg = 0; dg < 16; ++dg)
      accpv[dg] = MFMA(pa, vstage[dg], accpv[dg]);
    // rotate adj/ax prefetch
    a4[0] = a4n[0]; a4[1] = a4n[1];
    ax4[0] = ax4n[0]; ax4[1] = ax4n[1];
    __syncthreads();  // drains stage (vmcnt 0) -> sH ready for next tile
  }
  // ---- emit partials ----
  if (q0 == 0) {
    mPart[pidx * NN + qrow] = m_run;
    lPart[pidx * NN + qrow] = l_run;
  }
  short* np = numPart + (size_t)pidx * NN * DD;
#pragma unroll
  for (int dg = 0; dg < 16; ++dg)
#pragma unroll
    for (int r = 0; r < 4; ++r)
      np[(size_t)(row0 + wr * 16 + crow + r) * DD + dg * 16 + l15] =
          f2bf(accpv[dg][r]);
}

// hp = (sum_i num_i * exp(m_i - m*)) / (sum_i l_i * exp(m_i - m*))
__global__ __launch_bounds__(256) void combine_kernel(
    const short* __restrict__ numPart, const float* __restrict__ mPart,
    const float* __restrict__ lPart, short* __restrict__ hp) {
  const int row = blockIdx.x;
  const int col = threadIdx.x;
  float m[NPART], l[NPART];
  float ms = -__builtin_inff();
#pragma unroll
  for (int i = 0; i < NPART; ++i) {
    m[i] = mPart[i * NN + row];
    l[i] = lPart[i * NN + row];
    ms = fmaxf(ms, m[i]);
  }
  float denom = 0.f, num = 0.f;
  const size_t idx = (size_t)row * DD + col;
#pragma unroll
  for (int i = 0; i < NPART; ++i) {
    float wgt = __expf(m[i] - ms);
    denom += l[i] * wgt;
    num += bf2f(numPart[(size_t)i * NN * DD + idx]) * wgt;
  }
  hp[idx] = f2bf(num / denom);
}

extern "C" void kernel_launch(void* const* d_in, const int* in_sizes, int n_in,
                              void* d_out, int out_size, void* d_ws, size_t ws_size,
                              hipStream_t stream) {
  const float* feat = (const float*)d_in[0];
  const int*   adj  = (const int*)d_in[1];
  const float* W    = (const float*)d_in[2];
  const float* a1   = (const float*)d_in[3];
  const float* a2   = (const float*)d_in[4];
  const float* a12  = (const float*)d_in[5];
  const float* W1   = (const float*)d_in[6];
  const float* W2   = (const float*)d_in[7];
  float* out = (float*)d_out;
  (void)in_sizes; (void)n_in; (void)out_size; (void)ws_size;

  char* ws = (char*)d_ws;
  size_t off = 0;
  auto alloc = [&](size_t b) { void* p = ws + off; off += (b + 255) & ~(size_t)255; return p; };
  short* featHi = (short*)alloc((size_t)NN * DD * 2);
  short* featLo = (short*)alloc((size_t)NN * DD * 2);
  short* fT     = (short*)alloc((size_t)NN * DD * 2);
  short* hHi    = (short*)alloc((size_t)NN * DD * 2);
  short* hLo    = (short*)alloc((size_t)NN * DD * 2);
  short* gHi    = (short*)alloc((size_t)NN * DD * 2);
  short* gLo    = (short*)alloc((size_t)NN * DD * 2);
  short* hp     = (short*)alloc((size_t)NN * DD * 2);
  short* WTh    = (short*)alloc((size_t)DD * DD * 2);
  short* WTl    = (short*)alloc((size_t)DD * DD * 2);
  short* A12Th  = (short*)alloc((size_t)DD * DD * 2);
  short* A12Tl  = (short*)alloc((size_t)DD * DD * 2);
  short* W1T    = (short*)alloc((size_t)DD * DD * 2);
  short* W2T    = (short*)alloc((size_t)DD * DD * 2);
  float* axv    = (float*)alloc((size_t)NN * 4);
  float* ayv    = (float*)alloc((size_t)NN * 4);
  short* numPart = (short*)alloc((size_t)NPART * NN * DD * 2);
  float* mPart   = (float*)alloc((size_t)NPART * NN * 4);
  float* lPart   = (float*)alloc((size_t)NPART * NN * 4);

  cvt_split_kernel<<<2048, 256, 0, stream>>>(feat, featHi, featLo, NN * DD);
  featT_kernel<<<dim3(NN / 256, DD), 256, 0, stream>>>(feat, fT);
  transpose_split_kernel<<<DD, DD, 0, stream>>>(W, WTh, WTl);
  transpose_split_kernel<<<DD, DD, 0, stream>>>(a12, A12Th, A12Tl);
  transpose_split_kernel<<<DD, DD, 0, stream>>>(W1, W1T, nullptr);
  transpose_split_kernel<<<DD, DD, 0, stream>>>(W2, W2T, nullptr);
  gemm_bt64_kernel<<<dim3(NN / 64, DD / 64), 256, 0, stream>>>(
      featHi, featLo, WTh, WTl, nullptr, nullptr, hHi, hLo, nullptr, 0);
  gemm_bt64_kernel<<<dim3(NN / 64, DD / 64), 256, 0, stream>>>(
      hHi, hLo, A12Th, A12Tl, nullptr, nullptr, gHi, gLo, nullptr, 0);
  axay_kernel<<<NN / 4, 256, 0, stream>>>(hHi, hLo, a1, a2, axv, ayv);
  attn_kernel<<<dim3(NN / BM, NSPLIT), 256, 0, stream>>>(
      gHi, gLo, hHi, hLo, fT, axv, ayv, adj, numPart, mPart, lPart);
  combine_kernel<<<NN, DD, 0, stream>>>(numPart, mPart, lPart, hp);
  gemm_bt64_kernel<<<dim3(NN / 64, DD / 64), 256, 0, stream>>>(
      featHi, nullptr, W1T, nullptr, hp, W2T, nullptr, nullptr, out, 1);
}

// Round 5
// 401.018 us; speedup vs baseline: 1.3058x; 1.3058x over previous
//
#include <hip/hip_runtime.h>

// GAT layer, N=8192, D=256. R5: register-honest flash attention.
//  - KVB=32, BM=32, 4 waves; QK^T wave=(wr,sp)=16qx16kv; PV wave=32q x 64d.
//  - ghi hoisted (32 VGPR); g_lo staged in LDS; h hi+lo staged in LDS
//    (XOR-swizzled, conflict-free); cross-wave softmax via sS/sP exchange.
//  - loop-top vmcnt(0)+barrier drains stage; prefetches issued BEFORE stage
//    so no mid-tile vm drain. 3 lgkm barriers/tile. NSPLIT=4 + XCD swizzle.
// Split-bf16 (hi+lo) 3-term MFMA for the logit chain; plain bf16 elsewhere.

typedef __attribute__((ext_vector_type(8))) short bf16x8;
typedef __attribute__((ext_vector_type(4))) short s16x4;
typedef __attribute__((ext_vector_type(4))) float f32x4;

#define NN 8192
#define DD 256
#define NSPLIT 4
#define NPART 4
#define CHUNK (NN / NSPLIT)
#define KVB 32
#define BM 32
#define NT (CHUNK / KVB)

#define MFMA(a, b, c) __builtin_amdgcn_mfma_f32_16x16x32_bf16(a, b, c, 0, 0, 0)
#define BAR_LGKM() asm volatile("s_waitcnt lgkmcnt(0)\n\ts_barrier" ::: "memory")
#define BAR_VM() asm volatile("s_waitcnt vmcnt(0)\n\ts_barrier" ::: "memory")

__device__ __forceinline__ short f2bf(float f) {
  union { float f; unsigned u; } v; v.f = f;
  unsigned r = v.u + 0x7fffu + ((v.u >> 16) & 1u);  // RNE
  return (short)(r >> 16);
}
__device__ __forceinline__ float bf2f(short b) {
  union { unsigned u; float f; } v; v.u = ((unsigned)(unsigned short)b) << 16;
  return v.f;
}

typedef __attribute__((address_space(3))) unsigned lds_u32;
typedef const __attribute__((address_space(1))) unsigned glb_u32;
__device__ __forceinline__ void gl2lds16(const void* g, void* l) {
  __builtin_amdgcn_global_load_lds((glb_u32*)g, (lds_u32*)l, 16, 0, 0);
}

// f32 -> (hi, lo) bf16 split, elementwise
__global__ __launch_bounds__(256) void cvt_split_kernel(const float* __restrict__ in,
                                                        short* __restrict__ hi,
                                                        short* __restrict__ lo, int n) {
  for (int i = blockIdx.x * blockDim.x + threadIdx.x; i < n; i += gridDim.x * blockDim.x) {
    float f = in[i];
    short h = f2bf(f);
    hi[i] = h;
    lo[i] = f2bf(f - bf2f(h));
  }
}

// featT[c][i] = bf16(feat[i][c])
__global__ __launch_bounds__(256) void featT_kernel(const float* __restrict__ feat,
                                                    short* __restrict__ fT) {
  int c = blockIdx.y;
  int i = blockIdx.x * 256 + threadIdx.x;
  fT[c * NN + i] = f2bf(feat[i * DD + c]);
}

// 256x256 f32 -> transposed bf16 (optionally split hi/lo)
__global__ __launch_bounds__(256) void transpose_split_kernel(const float* __restrict__ in,
                                                              short* __restrict__ tHi,
                                                              short* __restrict__ tLo) {
  int r = blockIdx.x, c = threadIdx.x;
  float f = in[r * DD + c];
  short h = f2bf(f);
  tHi[c * DD + r] = h;
  if (tLo) tLo[c * DD + r] = f2bf(f - bf2f(h));
}

// C[64x64 tile] = A @ BT^T over K=256 (+optional split / second product / ELU)
__global__ __launch_bounds__(256) void gemm_bt64_kernel(
    const short* __restrict__ Ahi, const short* __restrict__ Alo,
    const short* __restrict__ BThi, const short* __restrict__ BTlo,
    const short* __restrict__ A2, const short* __restrict__ BT2,
    short* __restrict__ outHi, short* __restrict__ outLo,
    float* __restrict__ outF, int doElu) {
  const int lane = threadIdx.x & 63;
  const int w = threadIdx.x >> 6;
  const int l15 = lane & 15;
  const int koff = (lane >> 4) * 8;
  const int row0 = blockIdx.x * 64 + w * 16;
  const int col0 = blockIdx.y * 64;
  f32x4 acc[4] = {};
  const int aoff = (row0 + l15) * DD + koff;
#pragma unroll
  for (int kk = 0; kk < 8; ++kk) {
    bf16x8 ah = *(const bf16x8*)(Ahi + aoff + kk * 32);
#pragma unroll
    for (int cf = 0; cf < 4; ++cf) {
      int boff = (col0 + cf * 16 + l15) * DD + kk * 32 + koff;
      bf16x8 bh = *(const bf16x8*)(BThi + boff);
      acc[cf] = MFMA(ah, bh, acc[cf]);
      if (Alo) {
        bf16x8 al = *(const bf16x8*)(Alo + aoff + kk * 32);
        acc[cf] = MFMA(al, bh, acc[cf]);
      }
      if (BTlo) {
        bf16x8 bl = *(const bf16x8*)(BTlo + boff);
        acc[cf] = MFMA(ah, bl, acc[cf]);
      }
    }
  }
  if (A2) {
#pragma unroll
    for (int kk = 0; kk < 8; ++kk) {
      bf16x8 ah = *(const bf16x8*)(A2 + aoff + kk * 32);
#pragma unroll
      for (int cf = 0; cf < 4; ++cf) {
        bf16x8 bh = *(const bf16x8*)(BT2 + (col0 + cf * 16 + l15) * DD + kk * 32 + koff);
        acc[cf] = MFMA(ah, bh, acc[cf]);
      }
    }
  }
  const int crow = row0 + (lane >> 4) * 4;
#pragma unroll
  for (int cf = 0; cf < 4; ++cf) {
    int col = col0 + cf * 16 + l15;
#pragma unroll
    for (int r = 0; r < 4; ++r) {
      float v = acc[cf][r];
      if (doElu) v = (v > 0.f) ? v : expm1f(v);
      if (outF) outF[(crow + r) * DD + col] = v;
      if (outHi) {
        short hb = f2bf(v);
        outHi[(crow + r) * DD + col] = hb;
        if (outLo) outLo[(crow + r) * DD + col] = f2bf(v - bf2f(hb));
      }
    }
  }
}

// ax[i] = h[i,:]·a1, ay[i] = h[i,:]·a2
__global__ __launch_bounds__(256) void axay_kernel(const short* __restrict__ hHi,
                                                   const short* __restrict__ hLo,
                                                   const float* __restrict__ a1,
                                                   const float* __restrict__ a2,
                                                   float* __restrict__ ax,
                                                   float* __restrict__ ay) {
  const int lane = threadIdx.x & 63;
  const int w = threadIdx.x >> 6;
  const int row = blockIdx.x * 4 + w;
  float s1 = 0.f, s2 = 0.f;
#pragma unroll
  for (int j = 0; j < 4; ++j) {
    int k = lane * 4 + j;
    float hv = bf2f(hHi[row * DD + k]) + bf2f(hLo[row * DD + k]);
    s1 += hv * a1[k];
    s2 += hv * a2[k];
  }
#pragma unroll
  for (int m = 1; m < 64; m <<= 1) {
    s1 += __shfl_xor(s1, m);
    s2 += __shfl_xor(s2, m);
  }
  if (lane == 0) { ax[row] = s1; ay[row] = s2; }
}

// Flash attention, NSPLIT chunks, 32q x 32kv tiles, 4 waves.
__global__ __launch_bounds__(256, 2) void attn_kernel(
    const short* __restrict__ gHi, const short* __restrict__ gLo,
    const short* __restrict__ hHi, const short* __restrict__ hLo,
    const short* __restrict__ fT, const float* __restrict__ ax,
    const float* __restrict__ ay, const int* __restrict__ adj,
    short* __restrict__ numPart, float* __restrict__ mPart,
    float* __restrict__ lPart) {
  __shared__ short sH[KVB * DD];    // 16KB h-hi tile (512B rows, XOR-swizzled)
  __shared__ short sHlo[KVB * DD];  // 16KB h-lo tile
  __shared__ short sGlo[BM * DD];   // 16KB g-lo block (rows 512B, swizzled)
  __shared__ float sS[BM][36];      // 4.5KB S exchange
  __shared__ short sP[BM][40];      // 2.5KB P exchange
  __shared__ float sScale[BM];

  const int tid = threadIdx.x;
  const int lane = tid & 63;
  const int w = tid >> 6;
  const int wr = w >> 1, sp = w & 1;  // QK^T: row-half, kv-strip
  const int l15 = lane & 15;
  const int q0 = lane >> 4;
  const int crow = q0 * 4;

  // XCD-pair swizzle: chunk c -> XCDs {2c, 2c+1}; working set ~3MB < 4MB L2
  const int bid = blockIdx.x;
  const int chunk = (bid & 7) >> 1;
  const int rowblk = ((bid >> 3) << 1) | (bid & 1);
  const int row0 = rowblk * BM;
  const int jbase = chunk * CHUNK;

  // ---- hoist ghi for this wave's 16 q rows (32 VGPR) ----
  bf16x8 ghi[8];
  {
    const int go = (row0 + wr * 16 + l15) * DD + q0 * 8;
#pragma unroll
    for (int kk = 0; kk < 8; ++kk) ghi[kk] = *(const bf16x8*)(gHi + go + kk * 32);
  }
  float ay4[4];
#pragma unroll
  for (int r = 0; r < 4; ++r) ay4[r] = ay[row0 + wr * 16 + crow + r];

  // ---- stage g_lo block (once) + h tile 0, both swizzled ----
#pragma unroll
  for (int R = 0; R < 4; ++R) {
    int dstb = R * 4096 + tid * 16;
    int lr = dstb >> 9;
    int srcb = (dstb & 511) ^ ((lr & 7) << 4);
    gl2lds16(gLo + (row0 + lr) * DD + (srcb >> 1), (char*)sGlo + dstb);
  }
  auto stage = [&](int jrow) {
#pragma unroll
    for (int R = 0; R < 4; ++R) {
      int dstb = R * 4096 + tid * 16;
      int lr = dstb >> 9;
      int srcb = (dstb & 511) ^ ((lr & 7) << 4);
      int so = (jrow + lr) * DD + (srcb >> 1);
      gl2lds16(hHi + so, (char*)sH + dstb);
      gl2lds16(hLo + so, (char*)sHlo + dstb);
    }
  };
  stage(jbase);

  // ---- adj/ax prefetch for tile 0 (this lane's S column) ----
  const size_t adjrow = (size_t)(row0 + wr * 16 + crow) * NN;
  int a4[4];
  float axv;
  {
    int kb = jbase + sp * 16 + l15;
#pragma unroll
    for (int r = 0; r < 4; ++r) a4[r] = adj[adjrow + (size_t)r * NN + kb];
    axv = ax[kb];
  }

  // softmax role: 8 threads per row, 4 cols each
  const int srow = tid >> 3;
  const int sc4 = (tid & 7) * 4;
  float m_run = -__builtin_inff();
  float l_run = 0.f;
  f32x4 accpv[2][4] = {};  // [rg][df]: rows rg*16+crow+r, dims w*64+df*16+l15

  for (int t = 0; t < NT; ++t) {
    const int j0 = jbase + t * KVB;
    BAR_VM();  // stage(t) complete (covered by prev softmax+PV); block synced
    // ---- QK^T: 16q x 16kv, 3-term split, 2 alternating accumulators ----
    f32x4 aA = {}, aB = {};
    {
      const int lrB = sp * 16 + l15;
      const int rbB = lrB * 512, swzB = (lrB & 7) << 4;
      const int lrA = wr * 16 + l15;
      const int rbA = lrA * 512, swzA = (lrA & 7) << 4;
      __builtin_amdgcn_s_setprio(1);
#pragma unroll
      for (int kk = 0; kk < 8; ++kk) {
        const int slot = kk * 64 + q0 * 16;
        bf16x8 bh = *(const bf16x8*)((const char*)sH + rbB + (slot ^ swzB));
        bf16x8 bl = *(const bf16x8*)((const char*)sHlo + rbB + (slot ^ swzB));
        bf16x8 gl = *(const bf16x8*)((const char*)sGlo + rbA + (slot ^ swzA));
        if (kk & 1) {
          aB = MFMA(ghi[kk], bh, aB); aB = MFMA(gl, bh, aB); aB = MFMA(ghi[kk], bl, aB);
        } else {
          aA = MFMA(ghi[kk], bh, aA); aA = MFMA(gl, bh, aA); aA = MFMA(ghi[kk], bl, aA);
        }
      }
      __builtin_amdgcn_s_setprio(0);
    }
    // ---- mask + bias + leaky -> sS ----
#pragma unroll
    for (int r = 0; r < 4; ++r) {
      float v = aA[r] + aB[r] + axv + ay4[r];
      v = (v > 0.f) ? v : 0.2f * v;
      sS[wr * 16 + crow + r][sp * 16 + l15] = (a4[r] > 0) ? v : -9.0e15f;
    }
    BAR_LGKM();  // sS visible; sH/sGlo reads done
    // ---- prefetches for t(+1), issued BEFORE stage so no vm-drain ----
    bf16x8 vstage[4];
#pragma unroll
    for (int df = 0; df < 4; ++df)
      vstage[df] = *(const bf16x8*)(fT + (size_t)(w * 64 + df * 16 + l15) * NN + j0 + q0 * 8);
    int a4n[4];
    float axn;
    {
      int jn = (t + 1 < NT) ? (j0 + KVB) : jbase;
      int kb = jn + sp * 16 + l15;
#pragma unroll
      for (int r = 0; r < 4; ++r) a4n[r] = adj[adjrow + (size_t)r * NN + kb];
      axn = ax[kb];
    }
    if (t + 1 < NT) stage(j0 + KVB);
    // ---- softmax: row = tid>>3, 4 cols/thread, 3 shfl reduce ----
    {
      float4 sv = *(const float4*)(&sS[srow][sc4]);
      float tmax = fmaxf(fmaxf(sv.x, sv.y), fmaxf(sv.z, sv.w));
      tmax = fmaxf(tmax, __shfl_xor(tmax, 1));
      tmax = fmaxf(tmax, __shfl_xor(tmax, 2));
      tmax = fmaxf(tmax, __shfl_xor(tmax, 4));
      float m_new = fmaxf(m_run, tmax);
      float scale = __expf(m_run - m_new);
      float p0 = __expf(sv.x - m_new), p1 = __expf(sv.y - m_new);
      float p2 = __expf(sv.z - m_new), p3 = __expf(sv.w - m_new);
      float psum = (p0 + p1) + (p2 + p3);
      psum += __shfl_xor(psum, 1);
      psum += __shfl_xor(psum, 2);
      psum += __shfl_xor(psum, 4);
      l_run = l_run * scale + psum;
      m_run = m_new;
      s16x4 pk = { f2bf(p0), f2bf(p1), f2bf(p2), f2bf(p3) };
      *(s16x4*)(&sP[srow][sc4]) = pk;
      if ((tid & 7) == 0) sScale[srow] = scale;
    }
    BAR_LGKM();  // sP/sScale visible
    // ---- PV: rescale + 8 MFMA (A = sP rows, B = vstage) ----
    {
      float4 sc0 = *(const float4*)(&sScale[crow]);
      float4 sc1 = *(const float4*)(&sScale[16 + crow]);
      const float* scp[2] = { &sc0.x, &sc1.x };
#pragma unroll
      for (int rg = 0; rg < 2; ++rg)
#pragma unroll
        for (int df = 0; df < 4; ++df)
#pragma unroll
          for (int r = 0; r < 4; ++r) accpv[rg][df][r] *= scp[rg][r];
      bf16x8 pa0 = *(const bf16x8*)(&sP[l15][q0 * 8]);
      bf16x8 pa1 = *(const bf16x8*)(&sP[16 + l15][q0 * 8]);
      __builtin_amdgcn_s_setprio(1);
#pragma unroll
      for (int df = 0; df < 4; ++df) {
        accpv[0][df] = MFMA(pa0, vstage[df], accpv[0][df]);
        accpv[1][df] = MFMA(pa1, vstage[df], accpv[1][df]);
      }
      __builtin_amdgcn_s_setprio(0);
    }
#pragma unroll
    for (int r = 0; r < 4; ++r) a4[r] = a4n[r];
    axv = axn;
  }
  // ---- emit partials ----
  if ((tid & 7) == 0) {
    mPart[chunk * NN + row0 + srow] = m_run;
    lPart[chunk * NN + row0 + srow] = l_run;
  }
  short* np = numPart + (size_t)chunk * NN * DD;
#pragma unroll
  for (int rg = 0; rg < 2; ++rg)
#pragma unroll
    for (int df = 0; df < 4; ++df) {
      int col = w * 64 + df * 16 + l15;
#pragma unroll
      for (int r = 0; r < 4; ++r)
        np[(size_t)(row0 + rg * 16 + crow + r) * DD + col] = f2bf(accpv[rg][df][r]);
    }
}

// hp = (sum_i num_i * exp(m_i - m*)) / (sum_i l_i * exp(m_i - m*))
__global__ __launch_bounds__(256) void combine_kernel(
    const short* __restrict__ numPart, const float* __restrict__ mPart,
    const float* __restrict__ lPart, short* __restrict__ hp) {
  const int row = blockIdx.x;
  const int col = threadIdx.x;
  float m[NPART], l[NPART];
  float ms = -__builtin_inff();
#pragma unroll
  for (int i = 0; i < NPART; ++i) {
    m[i] = mPart[i * NN + row];
    l[i] = lPart[i * NN + row];
    ms = fmaxf(ms, m[i]);
  }
  float denom = 0.f, num = 0.f;
  const size_t idx = (size_t)row * DD + col;
#pragma unroll
  for (int i = 0; i < NPART; ++i) {
    float wgt = __expf(m[i] - ms);
    denom += l[i] * wgt;
    num += bf2f(numPart[(size_t)i * NN * DD + idx]) * wgt;
  }
  hp[idx] = f2bf(num / denom);
}

extern "C" void kernel_launch(void* const* d_in, const int* in_sizes, int n_in,
                              void* d_out, int out_size, void* d_ws, size_t ws_size,
                              hipStream_t stream) {
  const float* feat = (const float*)d_in[0];
  const int*   adj  = (const int*)d_in[1];
  const float* W    = (const float*)d_in[2];
  const float* a1   = (const float*)d_in[3];
  const float* a2   = (const float*)d_in[4];
  const float* a12  = (const float*)d_in[5];
  const float* W1   = (const float*)d_in[6];
  const float* W2   = (const float*)d_in[7];
  float* out = (float*)d_out;
  (void)in_sizes; (void)n_in; (void)out_size; (void)ws_size;

  char* ws = (char*)d_ws;
  size_t off = 0;
  auto alloc = [&](size_t b) { void* p = ws + off; off += (b + 255) & ~(size_t)255; return p; };
  short* featHi = (short*)alloc((size_t)NN * DD * 2);
  short* featLo = (short*)alloc((size_t)NN * DD * 2);
  short* fT     = (short*)alloc((size_t)NN * DD * 2);
  short* hHi    = (short*)alloc((size_t)NN * DD * 2);
  short* hLo    = (short*)alloc((size_t)NN * DD * 2);
  short* gHi    = (short*)alloc((size_t)NN * DD * 2);
  short* gLo    = (short*)alloc((size_t)NN * DD * 2);
  short* hp     = (short*)alloc((size_t)NN * DD * 2);
  short* WTh    = (short*)alloc((size_t)DD * DD * 2);
  short* WTl    = (short*)alloc((size_t)DD * DD * 2);
  short* A12Th  = (short*)alloc((size_t)DD * DD * 2);
  short* A12Tl  = (short*)alloc((size_t)DD * DD * 2);
  short* W1T    = (short*)alloc((size_t)DD * DD * 2);
  short* W2T    = (short*)alloc((size_t)DD * DD * 2);
  float* axv    = (float*)alloc((size_t)NN * 4);
  float* ayv    = (float*)alloc((size_t)NN * 4);
  short* numPart = (short*)alloc((size_t)NPART * NN * DD * 2);
  float* mPart   = (float*)alloc((size_t)NPART * NN * 4);
  float* lPart   = (float*)alloc((size_t)NPART * NN * 4);

  cvt_split_kernel<<<2048, 256, 0, stream>>>(feat, featHi, featLo, NN * DD);
  featT_kernel<<<dim3(NN / 256, DD), 256, 0, stream>>>(feat, fT);
  transpose_split_kernel<<<DD, DD, 0, stream>>>(W, WTh, WTl);
  transpose_split_kernel<<<DD, DD, 0, stream>>>(a12, A12Th, A12Tl);
  transpose_split_kernel<<<DD, DD, 0, stream>>>(W1, W1T, nullptr);
  transpose_split_kernel<<<DD, DD, 0, stream>>>(W2, W2T, nullptr);
  gemm_bt64_kernel<<<dim3(NN / 64, DD / 64), 256, 0, stream>>>(
      featHi, featLo, WTh, WTl, nullptr, nullptr, hHi, hLo, nullptr, 0);
  gemm_bt64_kernel<<<dim3(NN / 64, DD / 64), 256, 0, stream>>>(
      hHi, hLo, A12Th, A12Tl, nullptr, nullptr, gHi, gLo, nullptr, 0);
  axay_kernel<<<NN / 4, 256, 0, stream>>>(hHi, hLo, a1, a2, axv, ayv);
  attn_kernel<<<dim3((NN / BM) * NSPLIT), 256, 0, stream>>>(
      gHi, gLo, hHi, hLo, fT, axv, ayv, adj, numPart, mPart, lPart);
  combine_kernel<<<NN, DD, 0, stream>>>(numPart, mPart, lPart, hp);
  gemm_bt64_kernel<<<dim3(NN / 64, DD / 64), 256, 0, stream>>>(
      featHi, nullptr, W1T, nullptr, hp, W2T, nullptr, nullptr, out, 1);
}